// Round 2
// baseline (1196.082 us; speedup 1.0000x reference)
//
#include <hip/hip_runtime.h>

typedef _Float16 f16x8 __attribute__((ext_vector_type(8)));
typedef _Float16 f16x4 __attribute__((ext_vector_type(4)));
typedef float f32x4 __attribute__((ext_vector_type(4)));

#define BN   65536   // B*N = 16*4096
#define MSZ  4096
#define TOPK 8

#define MFMA(a, b, c) __builtin_amdgcn_mfma_f32_16x16x32_f16(a, b, c, 0, 0, 0)

// ---------------------------------------------------------------------------
// Prep: fp32 -> fp16 flat convert (keys)
// ---------------------------------------------------------------------------
__global__ void cvt_f16(const float* __restrict__ src, _Float16* __restrict__ dst,
                        int n) {
    int i = blockIdx.x * 256 + threadIdx.x;
    if (i < n) dst[i] = (_Float16)src[i];
}

// ---------------------------------------------------------------------------
// Prep: dst[n*K + k] = (f16)src[k*N + n]
// ---------------------------------------------------------------------------
__global__ void cvt_transpose(const float* __restrict__ src, _Float16* __restrict__ dst,
                              int K, int N) {
    int i = blockIdx.x * 256 + threadIdx.x;
    if (i < K * N) {
        int k = i / N, n = i - k * N;
        dst[n * K + k] = (_Float16)src[i];
    }
}

// ---------------------------------------------------------------------------
// Packed selection key: [31:12] = ordered-uint fp32 score (truncated),
// [11:0] = ~idx (12 bits) -> bigger key = higher score, ties: lower idx wins.
// ---------------------------------------------------------------------------
__device__ __forceinline__ unsigned pack_key(float s, unsigned inv12) {
    unsigned u = __float_as_uint(s);
    unsigned m = (unsigned)(((int)u) >> 31) | 0x80000000u;
    unsigned k = u ^ m;                       // ordered mapping
    return (k & 0xFFFFF000u) | inv12;
}

// v_med3_u32: single-instruction sorted-list insert step.
__device__ __forceinline__ unsigned med3u(unsigned a, unsigned b, unsigned c) {
    unsigned d;
    asm("v_med3_u32 %0, %1, %2, %3" : "=v"(d) : "v"(a), "v"(b), "v"(c));
    return d;
}

// Branchless insert into sorted-descending list t[0..N-1]:
// t'[p] = med3(t[p-1], t[p], key) (old t[p-1], high->low), t'[0] = max(t[0], key).
template <int N>
__device__ __forceinline__ void ins(unsigned* t, unsigned key) {
#pragma unroll
    for (int p = N - 1; p > 0; --p) t[p] = med3u(t[p - 1], t[p], key);
    t[0] = (t[0] > key) ? t[0] : key;
}

// ---------------------------------------------------------------------------
// Fully fused: proj -> sim -> top8 -> softmax -> gather -> MLP1 -> MLP2.
// 64 rows / block, 256 threads (4 waves). Each wave owns ONE 16-row tile and
// scans ALL 4096 keys for it -> per-wave butterfly yields exact top-8 with NO
// cross-wave merge. 2 blocks/CU (LDS 70656 B), __launch_bounds__(256,2) gives
// a 256-VGPR budget: tk[4][7]+af[8]+double-buffered key frags fit with no
// spills (round-1 kernel spilled ~77 MB of scratch at the 128-reg budget).
// ---------------------------------------------------------------------------
__global__ __launch_bounds__(256, 2) void fused_all(
        const float*    __restrict__ query,   // BN x 256 fp32
        const _Float16* __restrict__ keysH,   // 4096 x 256 f16 (ws)
        const float*    __restrict__ vals,    // 4096 x 256 fp32
        const _Float16* __restrict__ WqT,     // 256 x 256 f16 (ws, transposed)
        const float*    __restrict__ bq,
        const _Float16* __restrict__ W1T,     // 256 x 512 f16 (ws, transposed)
        const float*    __restrict__ b1,
        const _Float16* __restrict__ W2T,     // 256 x 256 f16 (ws, transposed)
        const float*    __restrict__ b2,
        float* __restrict__ out)              // BN x 256 fp32
{
    constexpr int ROWS = 64;
    __shared__ __attribute__((aligned(16))) _Float16 AA[ROWS][520];  // 66560 B
    __shared__ float Fs[ROWS][TOPK];                                 //  2048 B
    __shared__ int   Fi[ROWS][TOPK];                                 //  2048 B

    const int tid  = threadIdx.x;
    const int lane = tid & 63, quad = lane >> 4, l16 = lane & 15, wave = tid >> 6;
    const size_t row0 = (size_t)blockIdx.x * ROWS;

    // ---- P0: stage 64 query rows (fp32 -> f16) into AA[:, 0:256) ----
    for (int v = tid; v < 4096; v += 256) {
        int r = v >> 6, c = (v & 63) * 4;
        float4 f = *(const float4*)(query + (row0 + r) * 256 + c);
        f16x4 h = {(_Float16)f.x, (_Float16)f.y, (_Float16)f.z, (_Float16)f.w};
        *(f16x4*)&AA[r][c] = h;
    }
    __syncthreads();

    // ---- P1: qproj = query @ Wq + bq -> AA[:, 256:512) ----
    {
        f32x4 acc[4][4];
#pragma unroll
        for (int rt = 0; rt < 4; ++rt)
#pragma unroll
            for (int nt = 0; nt < 4; ++nt)
                acc[rt][nt] = (f32x4){0.f, 0.f, 0.f, 0.f};
#pragma unroll
        for (int kf = 0; kf < 8; ++kf) {
            f16x8 a[4];
#pragma unroll
            for (int rt = 0; rt < 4; ++rt)
                a[rt] = *(const f16x8*)&AA[rt * 16 + l16][kf * 32 + quad * 8];
#pragma unroll
            for (int nt = 0; nt < 4; ++nt) {
                int n0 = wave * 16 + nt * 64;
                f16x8 b = *(const f16x8*)(WqT + (size_t)(n0 + l16) * 256 + kf * 32 + quad * 8);
#pragma unroll
                for (int rt = 0; rt < 4; ++rt)
                    acc[rt][nt] = MFMA(a[rt], b, acc[rt][nt]);
            }
        }
#pragma unroll
        for (int nt = 0; nt < 4; ++nt) {
            int col = wave * 16 + nt * 64 + l16;
            float bv = bq[col];
#pragma unroll
            for (int rt = 0; rt < 4; ++rt)
#pragma unroll
                for (int r = 0; r < 4; ++r)
                    AA[rt * 16 + quad * 4 + r][256 + col] = (_Float16)(acc[rt][nt][r] + bv);
        }
    }
    __syncthreads();

    // ---- P2: sim = qproj @ keys^T. Wave handles rows wave*16..+15 over ALL
    // 4096 keys, 16 keys/half-iter, double-buffered key frags. Barrier-free.
    f16x8 af[8];
#pragma unroll
    for (int nk = 0; nk < 8; ++nk)
        af[nk] = *(const f16x8*)&AA[wave * 16 + l16][256 + nk * 32 + quad * 8];

    unsigned tk[4][7];   // 4 streams: rows quad*4+r, this lane's key subset
#pragma unroll
    for (int s = 0; s < 4; ++s)
#pragma unroll
        for (int e = 0; e < 7; ++e) tk[s][e] = 0u;

    {
        const _Float16* kbase = keysH + (size_t)l16 * 256 + quad * 8;
        f16x8 bA[8], bB[8];
#pragma unroll
        for (int nk = 0; nk < 8; ++nk)
            bA[nk] = *(const f16x8*)(kbase + nk * 32);

        for (int m0 = 0; m0 < MSZ; m0 += 32) {
            // prefetch keys m0+16 while computing on m0
#pragma unroll
            for (int nk = 0; nk < 8; ++nk)
                bB[nk] = *(const f16x8*)(kbase + (size_t)(m0 + 16) * 256 + nk * 32);
            f32x4 acc = {0.f, 0.f, 0.f, 0.f};
#pragma unroll
            for (int nk = 0; nk < 8; ++nk) acc = MFMA(af[nk], bA[nk], acc);
            unsigned inv = (~(unsigned)(m0 + l16)) & 0xFFFu;
#pragma unroll
            for (int r = 0; r < 4; ++r) ins<7>(tk[r], pack_key(acc[r], inv));

            // prefetch keys m0+32 (wrap on last iter; harmless reload)
            int mn = (m0 + 32) & (MSZ - 1);
#pragma unroll
            for (int nk = 0; nk < 8; ++nk)
                bA[nk] = *(const f16x8*)(kbase + (size_t)mn * 256 + nk * 32);
            f32x4 acc2 = {0.f, 0.f, 0.f, 0.f};
#pragma unroll
            for (int nk = 0; nk < 8; ++nk) acc2 = MFMA(af[nk], bB[nk], acc2);
            unsigned inv2 = (~(unsigned)(m0 + 16 + l16)) & 0xFFFu;
#pragma unroll
            for (int r = 0; r < 4; ++r) ins<7>(tk[r], pack_key(acc2[r], inv2));
        }
    }

    // ---- in-register butterfly over the 16 l16 lanes (disjoint key sets).
    // Stage 1 (xor 1): rows {0,1} vs {2,3}; depth 7 -> 8.
    unsigned t8[2][8];
    {
        const int kh = l16 & 1;
#pragma unroll
        for (int j = 0; j < 2; ++j) {
#pragma unroll
            for (int e = 0; e < 7; ++e) t8[j][e] = kh ? tk[2 + j][e] : tk[j][e];
            t8[j][7] = 0u;
        }
#pragma unroll
        for (int j = 0; j < 2; ++j)
#pragma unroll
            for (int e = 0; e < 7; ++e) {
                unsigned snd = kh ? tk[j][e] : tk[2 + j][e];   // the pair we give away
                unsigned rcv = __shfl_xor(snd, 1);
                ins<8>(t8[j], rcv);
            }
    }
    // Stage 2 (xor 2): keep t8[k2], send the other (branchless via keep/oth).
    unsigned keep[8];
    {
        const int k2 = (l16 >> 1) & 1;
        unsigned oth[8];
#pragma unroll
        for (int e = 0; e < 8; ++e) {
            keep[e] = k2 ? t8[1][e] : t8[0][e];
            oth[e]  = k2 ? t8[0][e] : t8[1][e];
        }
#pragma unroll
        for (int e = 0; e < 8; ++e) {
            unsigned rcv = __shfl_xor(oth[e], 2);
            ins<8>(keep, rcv);
        }
    }
    // Stages 3,4 (xor 4, xor 8): same row, disjoint key windows; snapshot first.
#pragma unroll
    for (int st = 4; st <= 8; st <<= 1) {
        unsigned rcv[8];
#pragma unroll
        for (int e = 0; e < 8; ++e) rcv[e] = __shfl_xor(keep[e], st);
#pragma unroll
        for (int e = 0; e < 8; ++e) ins<8>(keep, rcv[e]);
    }
    // Lanes l16<4 each own one row: rr = ((l16&1)<<1) | ((l16>>1)&1).
    if (l16 < 4) {
        const int rr  = ((l16 & 1) << 1) | ((l16 >> 1) & 1);
        const int row = wave * 16 + quad * 4 + rr;
#pragma unroll
        for (int k = 0; k < TOPK; ++k)
            Fi[row][k] = 4095 - (int)(keep[k] & 0xFFFu);
    }
    __syncthreads();

    // ---- recompute accurate fp32 scores + softmax weights (2 passes) ----
#pragma unroll
    for (int half = 0; half < 2; ++half) {
        int r = (tid >> 3) + half * 32, j = tid & 7;
        int idx = Fi[r][j] & (MSZ - 1);
        const f16x8* kp = (const f16x8*)(keysH + (size_t)idx * 256);
        float s = 0.f;
#pragma unroll
        for (int v = 0; v < 32; ++v) {
            f16x8 kv = kp[v];
            f16x8 qv = *(const f16x8*)&AA[r][256 + v * 8];
#pragma unroll
            for (int e = 0; e < 8; ++e) s += (float)qv[e] * (float)kv[e];
        }
        float mx = s;
#pragma unroll
        for (int off = 1; off < 8; off <<= 1) mx = fmaxf(mx, __shfl_xor(mx, off));
        float w = __expf(s - mx);
        float z = w;
#pragma unroll
        for (int off = 1; off < 8; off <<= 1) z += __shfl_xor(z, off);
        Fs[r][j] = w / z;
    }
    __syncthreads();

    // ---- P3: weighted gather of values (fp32) -> AA[:, 256:512) (2 passes) ----
#pragma unroll
    for (int half = 0; half < 2; ++half) {
        const int r = (tid >> 3) + half * 32, f0 = (tid & 7) * 32;
        float rv[32];
#pragma unroll
        for (int t = 0; t < 32; ++t) rv[t] = 0.f;
        for (int jj = 0; jj < TOPK; ++jj) {
            float wgt = Fs[r][jj];
            int idx = Fi[r][jj] & (MSZ - 1);
            const float4* vp = (const float4*)(vals + (size_t)idx * 256 + f0);
#pragma unroll
            for (int vv = 0; vv < 8; ++vv) {
                float4 vb = vp[vv];
                rv[vv * 4 + 0] += wgt * vb.x;
                rv[vv * 4 + 1] += wgt * vb.y;
                rv[vv * 4 + 2] += wgt * vb.z;
                rv[vv * 4 + 3] += wgt * vb.w;
            }
        }
#pragma unroll
        for (int t = 0; t < 32; ++t) AA[r][256 + f0 + t] = (_Float16)rv[t];
    }
    __syncthreads();

    // ---- P4: h = relu([query|retrieved] @ W1 + b1) -> AA[:, 0:256) ----
    {
        f32x4 acc[4][4];
#pragma unroll
        for (int rt = 0; rt < 4; ++rt)
#pragma unroll
            for (int nt = 0; nt < 4; ++nt)
                acc[rt][nt] = (f32x4){0.f, 0.f, 0.f, 0.f};
#pragma unroll
        for (int kf = 0; kf < 16; ++kf) {
            f16x8 a[4];
#pragma unroll
            for (int rt = 0; rt < 4; ++rt)
                a[rt] = *(const f16x8*)&AA[rt * 16 + l16][kf * 32 + quad * 8];
#pragma unroll
            for (int nt = 0; nt < 4; ++nt) {
                int n0 = wave * 16 + nt * 64;
                f16x8 b = *(const f16x8*)(W1T + (size_t)(n0 + l16) * 512 + kf * 32 + quad * 8);
#pragma unroll
                for (int rt = 0; rt < 4; ++rt)
                    acc[rt][nt] = MFMA(a[rt], b, acc[rt][nt]);
            }
        }
        __syncthreads();  // drain AA reads before overwriting cols 0:256
#pragma unroll
        for (int nt = 0; nt < 4; ++nt) {
            int col = wave * 16 + nt * 64 + l16;
            float bv = b1[col];
#pragma unroll
            for (int rt = 0; rt < 4; ++rt)
#pragma unroll
                for (int r = 0; r < 4; ++r)
                    AA[rt * 16 + quad * 4 + r][col] =
                        (_Float16)fmaxf(acc[rt][nt][r] + bv, 0.f);
        }
    }
    __syncthreads();

    // ---- P5: out = h @ W2 + b2 -> global (fp32) ----
    {
        f32x4 acc[4][4];
#pragma unroll
        for (int rt = 0; rt < 4; ++rt)
#pragma unroll
            for (int nt = 0; nt < 4; ++nt)
                acc[rt][nt] = (f32x4){0.f, 0.f, 0.f, 0.f};
#pragma unroll
        for (int kf = 0; kf < 8; ++kf) {
            f16x8 a[4];
#pragma unroll
            for (int rt = 0; rt < 4; ++rt)
                a[rt] = *(const f16x8*)&AA[rt * 16 + l16][kf * 32 + quad * 8];
#pragma unroll
            for (int nt = 0; nt < 4; ++nt) {
                int n0 = wave * 16 + nt * 64;
                f16x8 b = *(const f16x8*)(W2T + (size_t)(n0 + l16) * 256 + kf * 32 + quad * 8);
#pragma unroll
                for (int rt = 0; rt < 4; ++rt)
                    acc[rt][nt] = MFMA(a[rt], b, acc[rt][nt]);
            }
        }
#pragma unroll
        for (int nt = 0; nt < 4; ++nt) {
            int col = wave * 16 + nt * 64 + l16;
            float bv = b2[col];
#pragma unroll
            for (int rt = 0; rt < 4; ++rt)
#pragma unroll
                for (int r = 0; r < 4; ++r)
                    out[(row0 + rt * 16 + quad * 4 + r) * 256 + col] =
                        acc[rt][nt][r] + bv;
        }
    }
}

// ---------------------------------------------------------------------------
extern "C" void kernel_launch(void* const* d_in, const int* in_sizes, int n_in,
                              void* d_out, int out_size, void* d_ws, size_t ws_size,
                              hipStream_t stream) {
    const float* query = (const float*)d_in[0];
    const float* keys  = (const float*)d_in[1];
    const float* vals  = (const float*)d_in[2];
    const float* Wq    = (const float*)d_in[3];
    const float* bq    = (const float*)d_in[4];
    const float* W1    = (const float*)d_in[5];
    const float* b1    = (const float*)d_in[6];
    const float* W2    = (const float*)d_in[7];
    const float* b2    = (const float*)d_in[8];
    float* out = (float*)d_out;

    // ws layout (f16): keysH 2 MB @ 0 | WqT 128K | W1T 256K | W2T 128K = 2.5 MB
    char* ws = (char*)d_ws;
    _Float16* keysH = (_Float16*)(ws);
    _Float16* WqT   = (_Float16*)(ws + 2097152);
    _Float16* W1T   = (_Float16*)(ws + 2097152 + 131072);
    _Float16* W2T   = (_Float16*)(ws + 2097152 + 131072 + 262144);

    cvt_f16<<<4096, 256, 0, stream>>>(keys, keysH, MSZ * 256);
    cvt_transpose<<<256, 256, 0, stream>>>(Wq, WqT, 256, 256);
    cvt_transpose<<<512, 256, 0, stream>>>(W1, W1T, 512, 256);
    cvt_transpose<<<256, 256, 0, stream>>>(W2, W2T, 256, 256);

    fused_all<<<BN / 64, 256, 0, stream>>>(query, keysH, vals, WqT, bq,
                                           W1T, b1, W2T, b2, out);
}

// Round 3
// 538.409 us; speedup vs baseline: 2.2215x; 2.2215x over previous
//
#include <hip/hip_runtime.h>

typedef _Float16 f16x8 __attribute__((ext_vector_type(8)));
typedef _Float16 f16x4 __attribute__((ext_vector_type(4)));
typedef float f32x4 __attribute__((ext_vector_type(4)));

#define BN   65536   // B*N = 16*4096
#define MSZ  4096
#define TOPK 8

#define MFMA(a, b, c) __builtin_amdgcn_mfma_f32_16x16x32_f16(a, b, c, 0, 0, 0)

// ---------------------------------------------------------------------------
// Prep: fp32 -> fp16 flat convert (keys)
// ---------------------------------------------------------------------------
__global__ void cvt_f16(const float* __restrict__ src, _Float16* __restrict__ dst,
                        int n) {
    int i = blockIdx.x * 256 + threadIdx.x;
    if (i < n) dst[i] = (_Float16)src[i];
}

// ---------------------------------------------------------------------------
// Prep: dst[n*K + k] = (f16)src[k*N + n]
// ---------------------------------------------------------------------------
__global__ void cvt_transpose(const float* __restrict__ src, _Float16* __restrict__ dst,
                              int K, int N) {
    int i = blockIdx.x * 256 + threadIdx.x;
    if (i < K * N) {
        int k = i / N, n = i - k * N;
        dst[n * K + k] = (_Float16)src[i];
    }
}

// ---------------------------------------------------------------------------
// Packed selection key: [31:12] = ordered-uint fp32 score (truncated),
// [11:0] = ~idx (12 bits) -> bigger key = higher score, ties: lower idx wins.
// ---------------------------------------------------------------------------
__device__ __forceinline__ unsigned pack_key(float s, unsigned inv12) {
    unsigned u = __float_as_uint(s);
    unsigned m = (unsigned)(((int)u) >> 31) | 0x80000000u;
    unsigned k = u ^ m;                       // ordered mapping
    return (k & 0xFFFFF000u) | inv12;
}

// v_med3_u32: single-instruction sorted-list insert step.
__device__ __forceinline__ unsigned med3u(unsigned a, unsigned b, unsigned c) {
    unsigned d;
    asm("v_med3_u32 %0, %1, %2, %3" : "=v"(d) : "v"(a), "v"(b), "v"(c));
    return d;
}

// Branchless insert into sorted-descending list t[0..N-1].
template <int N>
__device__ __forceinline__ void ins(unsigned* t, unsigned key) {
#pragma unroll
    for (int p = N - 1; p > 0; --p) t[p] = med3u(t[p - 1], t[p], key);
    t[0] = (t[0] > key) ? t[0] : key;
}

// XOR-swizzled byte offset inside a 64-row x 512-byte LDS region (T2 pattern):
// spreads the 16 row-lanes of a ds_read_b128 across 8 bank-groups (2-way, free).
__device__ __forceinline__ int swz(int r, int cb) {
    return (r << 9) + (cb ^ ((r & 7) << 4));
}

// ---------------------------------------------------------------------------
// Fully fused: proj -> sim -> top8 -> softmax -> gather -> MLP1 -> MLP2.
// 64 rows / block, 4 waves; wave w owns rows w*16..+15. Keys are staged into
// LDS in 64-key double-buffered tiles (reg-staged, async-split: loads issued at
// iter start, ds_write after compute, ONE barrier per tile). All MFMA operand
// reads are swizzled ds_read_b128 (conflict-free). qproj lives in registers
// (af) during sim; top-8 redistribution, exact-score recompute, softmax and
// gather weights all stay in registers (no Fi/Fs LDS). LDS = 64 KB exactly,
// time-shared: A=[query|ktile0|query-reload|h], B=[qproj|ktile1|retrieved].
// ---------------------------------------------------------------------------
__global__ __launch_bounds__(256, 2) void fused_all(
        const float*    __restrict__ query,   // BN x 256 fp32
        const _Float16* __restrict__ keysH,   // 4096 x 256 f16 (ws)
        const float*    __restrict__ vals,    // 4096 x 256 fp32
        const _Float16* __restrict__ WqT,     // 256 x 256 f16 (ws, transposed)
        const float*    __restrict__ bq,
        const _Float16* __restrict__ W1T,     // 256 x 512 f16 (ws, transposed)
        const float*    __restrict__ b1,
        const _Float16* __restrict__ W2T,     // 256 x 256 f16 (ws, transposed)
        const float*    __restrict__ b2,
        float* __restrict__ out)              // BN x 256 fp32
{
    __shared__ __attribute__((aligned(16))) unsigned char SM[65536];
    unsigned char* const SA = SM;            // region A [0, 32K)
    unsigned char* const SB = SM + 32768;    // region B [32K, 64K)

    const int tid  = threadIdx.x;
    const int lane = tid & 63, quad = lane >> 4, l16 = lane & 15, wave = tid >> 6;
    const size_t row0 = (size_t)blockIdx.x * 64;

    // ---- P0: stage 64 query rows (fp32 -> f16, swizzled) into region A ----
#pragma unroll
    for (int j = 0; j < 8; ++j) {
        int u = (j << 8) + tid;
        int r = u >> 5, f = (u & 31) << 3;          // 8 f16 per unit
        float4 x = *(const float4*)(query + (row0 + r) * 256 + f);
        float4 y = *(const float4*)(query + (row0 + r) * 256 + f + 4);
        f16x8 h = {(_Float16)x.x, (_Float16)x.y, (_Float16)x.z, (_Float16)x.w,
                   (_Float16)y.x, (_Float16)y.y, (_Float16)y.z, (_Float16)y.w};
        *(f16x8*)(SA + swz(r, f << 1)) = h;
    }
    __syncthreads();

    // ---- P1: qproj = query @ Wq + bq -> region B (swizzled) ----
    {
        f32x4 acc[4][4];
#pragma unroll
        for (int rt = 0; rt < 4; ++rt)
#pragma unroll
            for (int nt = 0; nt < 4; ++nt)
                acc[rt][nt] = (f32x4){0.f, 0.f, 0.f, 0.f};
#pragma unroll
        for (int kf = 0; kf < 8; ++kf) {
            f16x8 a[4];
#pragma unroll
            for (int rt = 0; rt < 4; ++rt)
                a[rt] = *(const f16x8*)(SA + swz(rt * 16 + l16, kf * 64 + quad * 16));
#pragma unroll
            for (int nt = 0; nt < 4; ++nt) {
                int n0 = wave * 16 + nt * 64;
                f16x8 b = *(const f16x8*)(WqT + (size_t)(n0 + l16) * 256 + kf * 32 + quad * 8);
#pragma unroll
                for (int rt = 0; rt < 4; ++rt)
                    acc[rt][nt] = MFMA(a[rt], b, acc[rt][nt]);
            }
        }
#pragma unroll
        for (int nt = 0; nt < 4; ++nt) {
            int col = wave * 16 + nt * 64 + l16;
            float bv = bq[col];
#pragma unroll
            for (int rt = 0; rt < 4; ++rt)
#pragma unroll
                for (int r = 0; r < 4; ++r) {
                    int row = rt * 16 + quad * 4 + r;
                    *(_Float16*)(SB + swz(row, col * 2)) =
                        (_Float16)(acc[rt][nt][r] + bv);
                }
        }
    }
    __syncthreads();   // A-reads done (A free), qproj visible in B

    // ---- prologue: load af (qproj rows for THIS wave) + stage key tile 0 ----
    f16x8 af[8];
    {
        f16x8 kst[8];
#pragma unroll
        for (int j = 0; j < 8; ++j) {
            int u = (j << 8) + tid;
            int r = u >> 5, cb = (u & 31) << 4;
            kst[j] = *(const f16x8*)((const unsigned char*)keysH + (r << 9) + cb);
        }
#pragma unroll
        for (int nk = 0; nk < 8; ++nk)
            af[nk] = *(const f16x8*)(SB + swz(wave * 16 + l16, nk * 64 + quad * 16));
#pragma unroll
        for (int j = 0; j < 8; ++j) {
            int u = (j << 8) + tid;
            int r = u >> 5, cb = (u & 31) << 4;
            *(f16x8*)(SA + swz(r, cb)) = kst[j];
        }
    }
    __syncthreads();   // tile0 staged; all af loads complete (B writable)

    // ---- P2: sim over 64 double-buffered 64-key tiles ----
    unsigned tk[4][7];   // 4 streams: rows quad*4+r, keys == l16 (mod 16)
#pragma unroll
    for (int s = 0; s < 4; ++s)
#pragma unroll
        for (int e = 0; e < 7; ++e) tk[s][e] = 0u;

#pragma unroll 1
    for (int t = 0; t < 64; ++t) {
        const int cbase = (t & 1) << 15;
        const int nbase = 32768 - cbase;
        // issue next-tile loads (wrap on last iter; harmless)
        const unsigned char* ktg =
            (const unsigned char*)keysH + ((size_t)((t + 1) & 63) << 15);
        f16x8 kst[8];
#pragma unroll
        for (int j = 0; j < 8; ++j) {
            int u = (j << 8) + tid;
            int r = u >> 5, cb = (u & 31) << 4;
            kst[j] = *(const f16x8*)(ktg + (r << 9) + cb);
        }
        // compute current tile: 4 independent N-tiles of 16 keys
        const unsigned char* KB = SM + cbase;
#pragma unroll
        for (int n0 = 0; n0 < 64; n0 += 16) {
            f16x8 bf[8];
#pragma unroll
            for (int nk = 0; nk < 8; ++nk)
                bf[nk] = *(const f16x8*)(KB + swz(n0 + l16, nk * 64 + quad * 16));
            f32x4 acc = {0.f, 0.f, 0.f, 0.f};
#pragma unroll
            for (int nk = 0; nk < 8; ++nk) acc = MFMA(af[nk], bf[nk], acc);
            unsigned inv = (~(unsigned)((t << 6) + n0 + l16)) & 0xFFFu;
#pragma unroll
            for (int r = 0; r < 4; ++r) ins<7>(tk[r], pack_key(acc[r], inv));
        }
        // write staged tile into the other buffer
#pragma unroll
        for (int j = 0; j < 8; ++j) {
            int u = (j << 8) + tid;
            int r = u >> 5, cb = (u & 31) << 4;
            *(f16x8*)(SM + nbase + swz(r, cb)) = kst[j];
        }
        __syncthreads();
    }

    // ---- in-register butterfly over the 16 l16 lanes (exact: each wave saw
    // ALL keys for its 16 rows). Stage 1 (xor 1): 4 -> 2 streams, depth 7->8.
    unsigned t8[2][8];
    {
        const int kh = l16 & 1;
#pragma unroll
        for (int j = 0; j < 2; ++j) {
#pragma unroll
            for (int e = 0; e < 7; ++e) t8[j][e] = kh ? tk[2 + j][e] : tk[j][e];
            t8[j][7] = 0u;
        }
#pragma unroll
        for (int j = 0; j < 2; ++j)
#pragma unroll
            for (int e = 0; e < 7; ++e) {
                unsigned snd = kh ? tk[j][e] : tk[2 + j][e];
                unsigned rcv = __shfl_xor(snd, 1);
                ins<8>(t8[j], rcv);
            }
    }
    // Stage 2 (xor 2): 2 -> 1 stream.
    unsigned keep[8];
    {
        const int k2 = (l16 >> 1) & 1;
        unsigned oth[8];
#pragma unroll
        for (int e = 0; e < 8; ++e) {
            keep[e] = k2 ? t8[1][e] : t8[0][e];
            oth[e]  = k2 ? t8[0][e] : t8[1][e];
        }
#pragma unroll
        for (int e = 0; e < 8; ++e) ins<8>(keep, __shfl_xor(oth[e], 2));
    }
    // Stages 3,4 (xor 4, xor 8): disjoint key windows; snapshot first.
#pragma unroll
    for (int st = 4; st <= 8; st <<= 1) {
        unsigned rcv[8];
#pragma unroll
        for (int e = 0; e < 8; ++e) rcv[e] = __shfl_xor(keep[e], st);
#pragma unroll
        for (int e = 0; e < 8; ++e) ins<8>(keep, rcv[e]);
    }

    // ---- redistribute: lane (l16, quad) gets row l16's top-8 via shuffle ----
    // Row R owner: lane (R>>2)*16 + bitswap(R&3); all 4 quads broadcast-read.
    int idx[8];
    {
        const int src = ((l16 >> 2) << 4) + (((l16 & 1) << 1) | ((l16 >> 1) & 1));
#pragma unroll
        for (int e = 0; e < 8; ++e) {
            unsigned kb = __shfl(keep[e], src);
            idx[e] = 4095 - (int)(kb & 0xFFFu);
        }
    }

    // ---- exact fp32 scores from af (registers) + 4-lane reduce + softmax ----
    float wt[8];
    {
        float ps[8];
#pragma unroll
        for (int e = 0; e < 8; ++e) {
            const f16x8* kp = (const f16x8*)(keysH + (size_t)(idx[e] & (MSZ - 1)) * 256);
            float s = 0.f;
#pragma unroll
            for (int nk = 0; nk < 8; ++nk) {
                f16x8 kv = kp[nk * 4 + quad];
                f16x8 qv = af[nk];
#pragma unroll
                for (int i = 0; i < 8; ++i) s += (float)qv[i] * (float)kv[i];
            }
            ps[e] = s;
        }
#pragma unroll
        for (int e = 0; e < 8; ++e) {
            ps[e] += __shfl_xor(ps[e], 16);
            ps[e] += __shfl_xor(ps[e], 32);
        }
        float mx = ps[0];
#pragma unroll
        for (int e = 1; e < 8; ++e) mx = fmaxf(mx, ps[e]);
        float z = 0.f;
#pragma unroll
        for (int e = 0; e < 8; ++e) { wt[e] = __expf(ps[e] - mx); z += wt[e]; }
        float rz = 1.f / z;
#pragma unroll
        for (int e = 0; e < 8; ++e) wt[e] *= rz;
    }

    // ---- P3: weighted gather; lane (l16, quad) = row wave*16+l16, cols quad*64.. ----
    {
        float rv[64];
#pragma unroll
        for (int i = 0; i < 64; ++i) rv[i] = 0.f;
#pragma unroll
        for (int e = 0; e < 8; ++e) {
            const float4* vp = (const float4*)(vals + (size_t)(idx[e] & (MSZ - 1)) * 256 + quad * 64);
            float w = wt[e];
#pragma unroll
            for (int j = 0; j < 16; ++j) {
                float4 v = vp[j];
                rv[j * 4 + 0] += w * v.x; rv[j * 4 + 1] += w * v.y;
                rv[j * 4 + 2] += w * v.z; rv[j * 4 + 3] += w * v.w;
            }
        }
        // retrieved -> region B (swizzled); own-wave rows only (disjoint)
#pragma unroll
        for (int j = 0; j < 8; ++j) {
            f16x8 h = {(_Float16)rv[j * 8 + 0], (_Float16)rv[j * 8 + 1],
                       (_Float16)rv[j * 8 + 2], (_Float16)rv[j * 8 + 3],
                       (_Float16)rv[j * 8 + 4], (_Float16)rv[j * 8 + 5],
                       (_Float16)rv[j * 8 + 6], (_Float16)rv[j * 8 + 7]};
            *(f16x8*)(SB + swz(wave * 16 + l16, quad * 128 + (j << 4))) = h;
        }
    }
    // ---- reload raw query (fp32->f16) into region A ----
#pragma unroll
    for (int j = 0; j < 8; ++j) {
        int u = (j << 8) + tid;
        int r = u >> 5, f = (u & 31) << 3;
        float4 x = *(const float4*)(query + (row0 + r) * 256 + f);
        float4 y = *(const float4*)(query + (row0 + r) * 256 + f + 4);
        f16x8 h = {(_Float16)x.x, (_Float16)x.y, (_Float16)x.z, (_Float16)x.w,
                   (_Float16)y.x, (_Float16)y.y, (_Float16)y.z, (_Float16)y.w};
        *(f16x8*)(SA + swz(r, f << 1)) = h;
    }
    __syncthreads();

    // ---- P4: h = relu([query|retrieved] @ W1 + b1) -> region A ----
    {
        f32x4 acc[4][4];
#pragma unroll
        for (int rt = 0; rt < 4; ++rt)
#pragma unroll
            for (int nt = 0; nt < 4; ++nt)
                acc[rt][nt] = (f32x4){0.f, 0.f, 0.f, 0.f};
#pragma unroll
        for (int kf = 0; kf < 16; ++kf) {
            const unsigned char* base = (kf < 8) ? SA : SB;
            const int cb = (kf & 7) * 64 + quad * 16;
            f16x8 a[4];
#pragma unroll
            for (int rt = 0; rt < 4; ++rt)
                a[rt] = *(const f16x8*)(base + swz(rt * 16 + l16, cb));
#pragma unroll
            for (int nt = 0; nt < 4; ++nt) {
                int n0 = wave * 16 + nt * 64;
                f16x8 b = *(const f16x8*)(W1T + (size_t)(n0 + l16) * 512 + kf * 32 + quad * 8);
#pragma unroll
                for (int rt = 0; rt < 4; ++rt)
                    acc[rt][nt] = MFMA(a[rt], b, acc[rt][nt]);
            }
        }
        __syncthreads();  // drain region A reads before overwriting with h
#pragma unroll
        for (int nt = 0; nt < 4; ++nt) {
            int col = wave * 16 + nt * 64 + l16;
            float bv = b1[col];
#pragma unroll
            for (int rt = 0; rt < 4; ++rt)
#pragma unroll
                for (int r = 0; r < 4; ++r) {
                    int row = rt * 16 + quad * 4 + r;
                    *(_Float16*)(SA + swz(row, col * 2)) =
                        (_Float16)fmaxf(acc[rt][nt][r] + bv, 0.f);
                }
        }
    }
    __syncthreads();

    // ---- P5: out = h @ W2 + b2 -> global (fp32) ----
    {
        f32x4 acc[4][4];
#pragma unroll
        for (int rt = 0; rt < 4; ++rt)
#pragma unroll
            for (int nt = 0; nt < 4; ++nt)
                acc[rt][nt] = (f32x4){0.f, 0.f, 0.f, 0.f};
#pragma unroll
        for (int kf = 0; kf < 8; ++kf) {
            f16x8 a[4];
#pragma unroll
            for (int rt = 0; rt < 4; ++rt)
                a[rt] = *(const f16x8*)(SA + swz(rt * 16 + l16, kf * 64 + quad * 16));
#pragma unroll
            for (int nt = 0; nt < 4; ++nt) {
                int n0 = wave * 16 + nt * 64;
                f16x8 b = *(const f16x8*)(W2T + (size_t)(n0 + l16) * 256 + kf * 32 + quad * 8);
#pragma unroll
                for (int rt = 0; rt < 4; ++rt)
                    acc[rt][nt] = MFMA(a[rt], b, acc[rt][nt]);
            }
        }
#pragma unroll
        for (int nt = 0; nt < 4; ++nt) {
            int col = wave * 16 + nt * 64 + l16;
            float bv = b2[col];
#pragma unroll
            for (int rt = 0; rt < 4; ++rt)
#pragma unroll
                for (int r = 0; r < 4; ++r)
                    out[(row0 + rt * 16 + quad * 4 + r) * 256 + col] =
                        acc[rt][nt][r] + bv;
        }
    }
}

// ---------------------------------------------------------------------------
extern "C" void kernel_launch(void* const* d_in, const int* in_sizes, int n_in,
                              void* d_out, int out_size, void* d_ws, size_t ws_size,
                              hipStream_t stream) {
    const float* query = (const float*)d_in[0];
    const float* keys  = (const float*)d_in[1];
    const float* vals  = (const float*)d_in[2];
    const float* Wq    = (const float*)d_in[3];
    const float* bq    = (const float*)d_in[4];
    const float* W1    = (const float*)d_in[5];
    const float* b1    = (const float*)d_in[6];
    const float* W2    = (const float*)d_in[7];
    const float* b2    = (const float*)d_in[8];
    float* out = (float*)d_out;

    // ws layout (f16): keysH 2 MB @ 0 | WqT 128K | W1T 256K | W2T 128K = 2.5 MB
    char* ws = (char*)d_ws;
    _Float16* keysH = (_Float16*)(ws);
    _Float16* WqT   = (_Float16*)(ws + 2097152);
    _Float16* W1T   = (_Float16*)(ws + 2097152 + 131072);
    _Float16* W2T   = (_Float16*)(ws + 2097152 + 131072 + 262144);

    cvt_f16<<<4096, 256, 0, stream>>>(keys, keysH, MSZ * 256);
    cvt_transpose<<<256, 256, 0, stream>>>(Wq, WqT, 256, 256);
    cvt_transpose<<<512, 256, 0, stream>>>(W1, W1T, 512, 256);
    cvt_transpose<<<256, 256, 0, stream>>>(W2, W2T, 256, 256);

    fused_all<<<BN / 64, 256, 0, stream>>>(query, keysH, vals, WqT, bq,
                                           W1T, b1, W2T, b2, out);
}

// Round 4
// 484.705 us; speedup vs baseline: 2.4677x; 1.1108x over previous
//
#include <hip/hip_runtime.h>

typedef _Float16 f16x8 __attribute__((ext_vector_type(8)));
typedef float f32x4 __attribute__((ext_vector_type(4)));

#define BN   65536   // B*N = 16*4096
#define MSZ  4096
#define TOPK 8

#define MFMA(a, b, c) __builtin_amdgcn_mfma_f32_16x16x32_f16(a, b, c, 0, 0, 0)

// XOR-swizzled byte offset in a [64 rows][512 B] LDS tile. Mixes row bit 3 so
// rows r and r+8 (the two l16-aliases of one ds_read_b128) land on different
// bank groups (round-3's swz had them bank-identical -> 35M conflict cycles).
__device__ __forceinline__ int swz2(int r, int cb) {
    return (r << 9) + (cb ^ ((((r >> 3) ^ r) & 7) << 4));
}

// ---------------------------------------------------------------------------
// Single prep kernel: keys -> f16 PRE-SWIZZLED tile image (so that a linear
// global_load_lds fill reproduces the swizzled LDS layout), plus W transposes.
// ---------------------------------------------------------------------------
__global__ void prep(const float* __restrict__ keys, _Float16* __restrict__ keysSW,
                     const float* __restrict__ Wq, _Float16* __restrict__ WqT,
                     const float* __restrict__ W1, _Float16* __restrict__ W1T,
                     const float* __restrict__ W2, _Float16* __restrict__ W2T) {
    const int b = blockIdx.x, tid = threadIdx.x;
    if (b < 512) {                      // keys: 4096 x 256 -> 64 tiles x 32 KB
        int g = b * 256 + tid;          // [0, 131072)
        int k = g >> 5, f8 = g & 31;
        float4 x = *(const float4*)(keys + (size_t)k * 256 + f8 * 8);
        float4 y = *(const float4*)(keys + (size_t)k * 256 + f8 * 8 + 4);
        f16x8 h = {(_Float16)x.x, (_Float16)x.y, (_Float16)x.z, (_Float16)x.w,
                   (_Float16)y.x, (_Float16)y.y, (_Float16)y.z, (_Float16)y.w};
        *(f16x8*)((char*)keysSW + ((size_t)(k >> 6) << 15) + swz2(k & 63, f8 * 16)) = h;
    } else if (b < 768) {               // Wq 256x256 transpose
        int i = (b - 512) * 256 + tid;
        int kk = i >> 8, n = i & 255;
        WqT[n * 256 + kk] = (_Float16)Wq[i];
    } else if (b < 1280) {              // W1 512x256 transpose
        int i = (b - 768) * 256 + tid;
        int kk = i >> 8, n = i & 255;
        W1T[n * 512 + kk] = (_Float16)W1[i];
    } else {                            // W2 256x256 transpose
        int i = (b - 1280) * 256 + tid;
        int kk = i >> 8, n = i & 255;
        W2T[n * 256 + kk] = (_Float16)W2[i];
    }
}

// ---------------------------------------------------------------------------
// Packed selection key: [31:12] = ordered-uint fp32 score (truncated),
// [11:0] = ~idx (12 bits) -> bigger key = higher score, ties: lower idx wins.
// ---------------------------------------------------------------------------
__device__ __forceinline__ unsigned pack_key(float s, unsigned inv12) {
    unsigned u = __float_as_uint(s);
    unsigned m = (unsigned)(((int)u) >> 31) | 0x80000000u;
    unsigned k = u ^ m;
    return (k & 0xFFFFF000u) | inv12;
}

// v_med3_u32: single-instruction sorted-list insert step.
__device__ __forceinline__ unsigned med3u(unsigned a, unsigned b, unsigned c) {
    unsigned d;
    asm("v_med3_u32 %0, %1, %2, %3" : "=v"(d) : "v"(a), "v"(b), "v"(c));
    return d;
}

template <int N>
__device__ __forceinline__ void ins(unsigned* t, unsigned key) {
#pragma unroll
    for (int p = N - 1; p > 0; --p) t[p] = med3u(t[p - 1], t[p], key);
    t[0] = (t[0] > key) ? t[0] : key;
}

// async global -> LDS, 16 B per lane (wave-uniform LDS base + lane*16).
__device__ __forceinline__ void load_lds16(const void* g, void* l) {
    __builtin_amdgcn_global_load_lds(
        (const __attribute__((address_space(1))) unsigned int*)g,
        (__attribute__((address_space(3))) unsigned int*)l, 16, 0, 0);
}

// ---------------------------------------------------------------------------
// Fully fused: proj -> sim -> top8 -> softmax -> gather -> MLP1 -> MLP2.
// 64 rows / block, 4 waves. Sim: wave w owns 32 rows (group w&1, two 16-row
// A-banks in regs) x key-half (w>>1) of each 64-key LDS tile -> 2 MFMA per
// ds_read_b128 (round 3 had 1:1). Tiles staged via global_load_lds from the
// PRE-SWIZZLED keysSW image (linear fill == swizzled layout), double-buffered,
// one barrier per tile. Per-row top-8 = in-register butterfly + one 2-way
// cross-wave LDS merge. LDS = 64 KB, 2 blocks/CU, 256-VGPR budget.
// ---------------------------------------------------------------------------
__global__ __launch_bounds__(256, 2) void fused_all(
        const float*    __restrict__ query,   // BN x 256 fp32
        const _Float16* __restrict__ keysSW,  // 64 tiles x 32 KB (ws, pre-swizzled)
        const float*    __restrict__ vals,    // 4096 x 256 fp32
        const _Float16* __restrict__ WqT,     // 256 x 256 f16 (ws, transposed)
        const float*    __restrict__ bq,
        const _Float16* __restrict__ W1T,     // 256 x 512 f16 (ws, transposed)
        const float*    __restrict__ b1,
        const _Float16* __restrict__ W2T,     // 256 x 256 f16 (ws, transposed)
        const float*    __restrict__ b2,
        float* __restrict__ out)              // BN x 256 fp32
{
    __shared__ __attribute__((aligned(16))) unsigned char SM[65536];
    unsigned char* const SA = SM;            // region A [0, 32K): query/tile0/Mrg/h
    unsigned char* const SB = SM + 32768;    // region B [32K, 64K): qproj/tile1/retr

    const int tid  = threadIdx.x;
    const int lane = tid & 63, quad = lane >> 4, l16 = lane & 15, wave = tid >> 6;
    const size_t row0 = (size_t)blockIdx.x * 64;

    // ---- P0: stage 64 query rows (fp32 -> f16, swizzled) into region A ----
#pragma unroll
    for (int j = 0; j < 8; ++j) {
        int u = (j << 8) + tid;
        int r = u >> 5, f = (u & 31) << 3;
        float4 x = *(const float4*)(query + (row0 + r) * 256 + f);
        float4 y = *(const float4*)(query + (row0 + r) * 256 + f + 4);
        f16x8 h = {(_Float16)x.x, (_Float16)x.y, (_Float16)x.z, (_Float16)x.w,
                   (_Float16)y.x, (_Float16)y.y, (_Float16)y.z, (_Float16)y.w};
        *(f16x8*)(SA + swz2(r, f << 1)) = h;
    }
    __syncthreads();

    // ---- P1: qproj = query @ Wq + bq -> region B (swizzled) ----
    {
        f32x4 acc[4][4];
#pragma unroll
        for (int rt = 0; rt < 4; ++rt)
#pragma unroll
            for (int nt = 0; nt < 4; ++nt)
                acc[rt][nt] = (f32x4){0.f, 0.f, 0.f, 0.f};
#pragma unroll
        for (int kf = 0; kf < 8; ++kf) {
            f16x8 a[4];
#pragma unroll
            for (int rt = 0; rt < 4; ++rt)
                a[rt] = *(const f16x8*)(SA + swz2(rt * 16 + l16, kf * 64 + quad * 16));
#pragma unroll
            for (int nt = 0; nt < 4; ++nt) {
                int n0 = wave * 16 + nt * 64;
                f16x8 b = *(const f16x8*)(WqT + (size_t)(n0 + l16) * 256 + kf * 32 + quad * 8);
#pragma unroll
                for (int rt = 0; rt < 4; ++rt)
                    acc[rt][nt] = MFMA(a[rt], b, acc[rt][nt]);
            }
        }
#pragma unroll
        for (int nt = 0; nt < 4; ++nt) {
            int col = wave * 16 + nt * 64 + l16;
            float bv = bq[col];
#pragma unroll
            for (int rt = 0; rt < 4; ++rt)
#pragma unroll
                for (int r = 0; r < 4; ++r) {
                    int row = rt * 16 + quad * 4 + r;
                    *(_Float16*)(SB + swz2(row, col * 2)) =
                        (_Float16)(acc[rt][nt][r] + bv);
                }
        }
    }
    __syncthreads();   // region A free, qproj visible in B

    // ---- prologue: af (32 qproj rows of group wave&1) + gload tile0 -> A ----
    f16x8 af0[8], af1[8];
    {
        const char* src = (const char*)keysSW + wave * 8192;
        char* dst = (char*)SA + wave * 8192;
#pragma unroll
        for (int j = 0; j < 8; ++j)
            load_lds16(src + j * 1024 + lane * 16, dst + j * 1024);
#pragma unroll
        for (int nk = 0; nk < 8; ++nk) {
            af0[nk] = *(const f16x8*)(SB + swz2((wave & 1) * 32 + l16,      nk * 64 + quad * 16));
            af1[nk] = *(const f16x8*)(SB + swz2((wave & 1) * 32 + 16 + l16, nk * 64 + quad * 16));
        }
    }
    __syncthreads();   // tile0 complete (vmcnt drained), af loaded (B writable)

    // ---- P2: sim over 64 double-buffered 64-key tiles ----
    unsigned tk[8][6];   // streams: local rows {quad*4+r} (bank0) / +16 (bank1)
#pragma unroll
    for (int s = 0; s < 8; ++s)
#pragma unroll
        for (int e = 0; e < 6; ++e) tk[s][e] = 0u;

    const int kh = (wave >> 1) * 32;     // this wave's key-half within a tile

#pragma unroll 1
    for (int t = 0; t < 64; ++t) {
        unsigned char* cur = SM + ((t & 1) << 15);
        unsigned char* nxt = SM + (((t + 1) & 1) << 15);
        // prefetch tile t+1 (async -> LDS; drained at this iter's barrier)
        {
            const char* src = (const char*)keysSW + ((size_t)((t + 1) & 63) << 15) + wave * 8192;
            char* dst = (char*)nxt + wave * 8192;
#pragma unroll
            for (int j = 0; j < 8; ++j)
                load_lds16(src + j * 1024 + lane * 16, dst + j * 1024);
        }
        // compute this wave's key-half: 2 chunks x (8 ds_read -> 16 MFMA)
#pragma unroll
        for (int c = 0; c < 2; ++c) {
            const int kl = kh + c * 16;
            f16x8 bf[8];
#pragma unroll
            for (int nk = 0; nk < 8; ++nk)
                bf[nk] = *(const f16x8*)(cur + swz2(kl + l16, nk * 64 + quad * 16));
            f32x4 a0 = {0.f, 0.f, 0.f, 0.f};
            f32x4 a1 = {0.f, 0.f, 0.f, 0.f};
#pragma unroll
            for (int nk = 0; nk < 8; ++nk) {
                a0 = MFMA(af0[nk], bf[nk], a0);
                a1 = MFMA(af1[nk], bf[nk], a1);
            }
            unsigned inv = (~(unsigned)((t << 6) + kl + l16)) & 0xFFFu;
#pragma unroll
            for (int r = 0; r < 4; ++r) ins<6>(tk[r],     pack_key(a0[r], inv));
#pragma unroll
            for (int r = 0; r < 4; ++r) ins<6>(tk[4 + r], pack_key(a1[r], inv));
        }
        __syncthreads();
    }

    // ---- in-register butterfly (16 l16 lanes; each wave saw its key-half) ----
    // Stage A (xor1): fold bank dim. depth 6 -> 7.
    unsigned m4[4][7];
    {
        const int kb = l16 & 1;
#pragma unroll
        for (int j = 0; j < 4; ++j) {
#pragma unroll
            for (int e = 0; e < 6; ++e) m4[j][e] = kb ? tk[4 + j][e] : tk[j][e];
            m4[j][6] = 0u;
#pragma unroll
            for (int e = 0; e < 6; ++e) {
                unsigned snd = kb ? tk[j][e] : tk[4 + j][e];
                ins<7>(m4[j], __shfl_xor(snd, 1));
            }
        }
    }
    // Stage B (xor2): fold row-pair. depth 7 -> 8.
    unsigned m2[2][8];
    {
        const int k2 = (l16 >> 1) & 1;
#pragma unroll
        for (int j = 0; j < 2; ++j) {
#pragma unroll
            for (int e = 0; e < 7; ++e) m2[j][e] = k2 ? m4[2 + j][e] : m4[j][e];
            m2[j][7] = 0u;
#pragma unroll
            for (int e = 0; e < 7; ++e) {
                unsigned snd = k2 ? m4[j][e] : m4[2 + j][e];
                ins<8>(m2[j], __shfl_xor(snd, 2));
            }
        }
    }
    // Stage C (xor4): fold row parity. depth 8.
    unsigned fm[8];
    {
        const int k3 = (l16 >> 2) & 1;
        unsigned oth[8];
#pragma unroll
        for (int e = 0; e < 8; ++e) {
            fm[e]  = k3 ? m2[1][e] : m2[0][e];
            oth[e] = k3 ? m2[0][e] : m2[1][e];
        }
#pragma unroll
        for (int e = 0; e < 8; ++e) ins<8>(fm, __shfl_xor(oth[e], 4));
    }
    // Stage D (xor8): merge key-window halves (snapshot both sides).
    {
        unsigned rcv[8];
#pragma unroll
        for (int e = 0; e < 8; ++e) rcv[e] = __shfl_xor(fm[e], 8);
#pragma unroll
        for (int e = 0; e < 8; ++e) ins<8>(fm, rcv[e]);
    }
    // Dump per-(row, key-half) top-8: lanes l16<8 own distinct local rows.
    // SA is dead (last prefetch target was wrap tile) -> Mrg lives there.
    if (l16 < 8) {
        const int rl  = quad * 4 + 2 * ((l16 >> 1) & 1) + ((l16 >> 2) & 1) + 16 * (l16 & 1);
        const int row = (wave & 1) * 32 + rl;
        unsigned* Mrg = (unsigned*)SA;
#pragma unroll
        for (int e = 0; e < 8; ++e) Mrg[((wave >> 1) * 64 + row) * 8 + e] = fm[e];
    }
    __syncthreads();

    // ---- 2-way cross-half merge (all lanes; quads duplicate -> broadcast) ----
    const int rmap = ((wave & 1) << 5) + ((wave & 2) << 3);  // w:0,1,2,3 -> 0,32,16,48
    int idx[8];
    {
        const unsigned* Mrg = (const unsigned*)SA;
        const int row = rmap + l16;
        unsigned f[8];
#pragma unroll
        for (int e = 0; e < 8; ++e) f[e] = Mrg[row * 8 + e];
#pragma unroll
        for (int e = 0; e < 8; ++e) ins<8>(f, Mrg[(64 + row) * 8 + e]);
#pragma unroll
        for (int e = 0; e < 8; ++e) idx[e] = 4095 - (int)(f[e] & 0xFFFu);
    }

    // ---- exact fp32 scores (qproj from af regs, keys from keysSW) + softmax ----
    float wt[8];
    {
        f16x8 afr[8];
        const bool hi = (wave & 2) != 0;   // row = rmap+l16 sits in af1 if w&2
#pragma unroll
        for (int nk = 0; nk < 8; ++nk) afr[nk] = hi ? af1[nk] : af0[nk];
        float ps[8];
#pragma unroll
        for (int e = 0; e < 8; ++e) {
            const unsigned char* kb =
                (const unsigned char*)keysSW + ((size_t)(idx[e] >> 6) << 15);
            const int kr = idx[e] & 63;
            float s = 0.f;
#pragma unroll
            for (int nk = 0; nk < 8; ++nk) {
                f16x8 kv = *(const f16x8*)(kb + swz2(kr, nk * 64 + quad * 16));
                f16x8 qv = afr[nk];
#pragma unroll
                for (int i = 0; i < 8; ++i) s += (float)qv[i] * (float)kv[i];
            }
            ps[e] = s;
        }
#pragma unroll
        for (int e = 0; e < 8; ++e) {      // reduce k-slices across quads
            ps[e] += __shfl_xor(ps[e], 16);
            ps[e] += __shfl_xor(ps[e], 32);
        }
        float mx = ps[0];
#pragma unroll
        for (int e = 1; e < 8; ++e) mx = fmaxf(mx, ps[e]);
        float z = 0.f;
#pragma unroll
        for (int e = 0; e < 8; ++e) { wt[e] = __expf(ps[e] - mx); z += wt[e]; }
        float rz = 1.f / z;
#pragma unroll
        for (int e = 0; e < 8; ++e) wt[e] *= rz;
    }

    // ---- P3: weighted gather; lane = row rmap+l16, cols quad*64.. -> SB ----
    {
        float rv[64];
#pragma unroll
        for (int i = 0; i < 64; ++i) rv[i] = 0.f;
#pragma unroll
        for (int e = 0; e < 8; ++e) {
            const float4* vp = (const float4*)(vals + (size_t)(idx[e] & (MSZ - 1)) * 256 + quad * 64);
            float w = wt[e];
#pragma unroll
            for (int j = 0; j < 16; ++j) {
                float4 v = vp[j];
                rv[j * 4 + 0] += w * v.x; rv[j * 4 + 1] += w * v.y;
                rv[j * 4 + 2] += w * v.z; rv[j * 4 + 3] += w * v.w;
            }
        }
        const int row = rmap + l16;
#pragma unroll
        for (int j = 0; j < 8; ++j) {
            f16x8 h = {(_Float16)rv[j * 8 + 0], (_Float16)rv[j * 8 + 1],
                       (_Float16)rv[j * 8 + 2], (_Float16)rv[j * 8 + 3],
                       (_Float16)rv[j * 8 + 4], (_Float16)rv[j * 8 + 5],
                       (_Float16)rv[j * 8 + 6], (_Float16)rv[j * 8 + 7]};
            *(f16x8*)(SB + swz2(row, quad * 128 + (j << 4))) = h;
        }
    }
    __syncthreads();   // all Mrg reads done -> region A writable

    // ---- reload raw query (fp32->f16) into region A ----
#pragma unroll
    for (int j = 0; j < 8; ++j) {
        int u = (j << 8) + tid;
        int r = u >> 5, f = (u & 31) << 3;
        float4 x = *(const float4*)(query + (row0 + r) * 256 + f);
        float4 y = *(const float4*)(query + (row0 + r) * 256 + f + 4);
        f16x8 h = {(_Float16)x.x, (_Float16)x.y, (_Float16)x.z, (_Float16)x.w,
                   (_Float16)y.x, (_Float16)y.y, (_Float16)y.z, (_Float16)y.w};
        *(f16x8*)(SA + swz2(r, f << 1)) = h;
    }
    __syncthreads();

    // ---- P4: h = relu([query|retrieved] @ W1 + b1) -> region A ----
    {
        f32x4 acc[4][4];
#pragma unroll
        for (int rt = 0; rt < 4; ++rt)
#pragma unroll
            for (int nt = 0; nt < 4; ++nt)
                acc[rt][nt] = (f32x4){0.f, 0.f, 0.f, 0.f};
#pragma unroll
        for (int kf = 0; kf < 16; ++kf) {
            const unsigned char* base = (kf < 8) ? SA : SB;
            const int cb = (kf & 7) * 64 + quad * 16;
            f16x8 a[4];
#pragma unroll
            for (int rt = 0; rt < 4; ++rt)
                a[rt] = *(const f16x8*)(base + swz2(rt * 16 + l16, cb));
#pragma unroll
            for (int nt = 0; nt < 4; ++nt) {
                int n0 = wave * 16 + nt * 64;
                f16x8 b = *(const f16x8*)(W1T + (size_t)(n0 + l16) * 512 + kf * 32 + quad * 8);
#pragma unroll
                for (int rt = 0; rt < 4; ++rt)
                    acc[rt][nt] = MFMA(a[rt], b, acc[rt][nt]);
            }
        }
        __syncthreads();  // drain region A reads before overwriting with h
#pragma unroll
        for (int nt = 0; nt < 4; ++nt) {
            int col = wave * 16 + nt * 64 + l16;
            float bv = b1[col];
#pragma unroll
            for (int rt = 0; rt < 4; ++rt)
#pragma unroll
                for (int r = 0; r < 4; ++r) {
                    int row = rt * 16 + quad * 4 + r;
                    *(_Float16*)(SA + swz2(row, col * 2)) =
                        (_Float16)fmaxf(acc[rt][nt][r] + bv, 0.f);
                }
        }
    }
    __syncthreads();

    // ---- P5: out = h @ W2 + b2 -> global (fp32) ----
    {
        f32x4 acc[4][4];
#pragma unroll
        for (int rt = 0; rt < 4; ++rt)
#pragma unroll
            for (int nt = 0; nt < 4; ++nt)
                acc[rt][nt] = (f32x4){0.f, 0.f, 0.f, 0.f};
#pragma unroll
        for (int kf = 0; kf < 8; ++kf) {
            f16x8 a[4];
#pragma unroll
            for (int rt = 0; rt < 4; ++rt)
                a[rt] = *(const f16x8*)(SA + swz2(rt * 16 + l16, kf * 64 + quad * 16));
#pragma unroll
            for (int nt = 0; nt < 4; ++nt) {
                int n0 = wave * 16 + nt * 64;
                f16x8 b = *(const f16x8*)(W2T + (size_t)(n0 + l16) * 256 + kf * 32 + quad * 8);
#pragma unroll
                for (int rt = 0; rt < 4; ++rt)
                    acc[rt][nt] = MFMA(a[rt], b, acc[rt][nt]);
            }
        }
#pragma unroll
        for (int nt = 0; nt < 4; ++nt) {
            int col = wave * 16 + nt * 64 + l16;
            float bv = b2[col];
#pragma unroll
            for (int rt = 0; rt < 4; ++rt)
#pragma unroll
                for (int r = 0; r < 4; ++r)
                    out[(row0 + rt * 16 + quad * 4 + r) * 256 + col] =
                        acc[rt][nt][r] + bv;
        }
    }
}

// ---------------------------------------------------------------------------
extern "C" void kernel_launch(void* const* d_in, const int* in_sizes, int n_in,
                              void* d_out, int out_size, void* d_ws, size_t ws_size,
                              hipStream_t stream) {
    const float* query = (const float*)d_in[0];
    const float* keys  = (const float*)d_in[1];
    const float* vals  = (const float*)d_in[2];
    const float* Wq    = (const float*)d_in[3];
    const float* bq    = (const float*)d_in[4];
    const float* W1    = (const float*)d_in[5];
    const float* b1    = (const float*)d_in[6];
    const float* W2    = (const float*)d_in[7];
    const float* b2    = (const float*)d_in[8];
    float* out = (float*)d_out;

    // ws layout (f16): keysSW 2 MB @ 0 | WqT 128K | W1T 256K | W2T 128K = 2.5 MB
    char* ws = (char*)d_ws;
    _Float16* keysSW = (_Float16*)(ws);
    _Float16* WqT    = (_Float16*)(ws + 2097152);
    _Float16* W1T    = (_Float16*)(ws + 2097152 + 131072);
    _Float16* W2T    = (_Float16*)(ws + 2097152 + 131072 + 262144);

    prep<<<1536, 256, 0, stream>>>(keys, keysSW, Wq, WqT, W1, W1T, W2, W2T);

    fused_all<<<BN / 64, 256, 0, stream>>>(query, keysSW, vals, WqT, bq,
                                           W1T, b1, W2T, b2, out);
}